// Round 9
// baseline (113.445 us; speedup 1.0000x reference)
//
#include <hip/hip_runtime.h>
#include <hip/hip_bf16.h>

// z = segment_sum( (x @ W_fc^T)[col], row )  -- alpha==1 (softmax over singleton dim)
// Round 9: drop CSR counting-sort (hist/scan/scan/fill) for one fixed-capacity
// bucketing pass (cap=64 >> Poisson(16) max; spill list for correctness).
// Fuse fc with bucket (independent, disjoint block ranges).
// Pipeline: zero -> fc||bucket -> gather4b -> spill_fix

#define CAP 64
#define SPILLCAP 65536

__device__ inline unsigned short f2bf(float f) {
    __hip_bfloat16 h = __float2bfloat16(f);
    return *reinterpret_cast<unsigned short*>(&h);
}

// ---------- zero: cnt[N] + spillcnt[1] ----------
__global__ void zero_kernel(int* __restrict__ a, int n) {
    int i = blockIdx.x * blockDim.x + threadIdx.x;
    int s = gridDim.x * blockDim.x;
    for (; i < n; i += s) a[i] = 0;
}

// ---------- fused: blocks [0,fcB) do fc (x@W^T -> bf16 y); rest bucket edges ----------
__global__ __launch_bounds__(256) void fc_bucket(
        const float* __restrict__ x, const float* __restrict__ Wfc,
        unsigned short* __restrict__ y, int N,
        const int* __restrict__ eidx, int* __restrict__ cnt, int* __restrict__ slots,
        int* __restrict__ spill, int* __restrict__ spillcnt, int E, int fcB) {
    if ((int)blockIdx.x < fcB) {
        // ---- fc: 16 rows/block ----
        __shared__ float sW[64][65];
        __shared__ float sX[16][64];
        for (int i = threadIdx.x; i < 4096; i += 256) sW[i >> 6][i & 63] = Wfc[i];
        int row0 = blockIdx.x << 4;
        for (int i = threadIdx.x; i < 1024; i += 256) {
            int r = i >> 6, k = i & 63, gr = row0 + r;
            sX[r][k] = (gr < N) ? x[(size_t)gr * 64 + k] : 0.f;
        }
        __syncthreads();
        int co = threadIdx.x & 63;
        int rq = threadIdx.x >> 6;
        float a0 = 0, a1 = 0, a2 = 0, a3 = 0;
#pragma unroll
        for (int k = 0; k < 64; ++k) {
            float w = sW[co][k];
            a0 = fmaf(w, sX[4 * rq + 0][k], a0);
            a1 = fmaf(w, sX[4 * rq + 1][k], a1);
            a2 = fmaf(w, sX[4 * rq + 2][k], a2);
            a3 = fmaf(w, sX[4 * rq + 3][k], a3);
        }
        int g = row0 + 4 * rq;
        if (g + 3 < N) {
            y[(size_t)(g + 0) * 64 + co] = f2bf(a0);
            y[(size_t)(g + 1) * 64 + co] = f2bf(a1);
            y[(size_t)(g + 2) * 64 + co] = f2bf(a2);
            y[(size_t)(g + 3) * 64 + co] = f2bf(a3);
        } else {
            if (g + 0 < N) y[(size_t)(g + 0) * 64 + co] = f2bf(a0);
            if (g + 1 < N) y[(size_t)(g + 1) * 64 + co] = f2bf(a1);
            if (g + 2 < N) y[(size_t)(g + 2) * 64 + co] = f2bf(a2);
        }
    } else {
        // ---- bucket: slot = atomicAdd(cnt[r]); slots[r*CAP+slot] = c ----
        int bid = (int)blockIdx.x - fcB;
        int nb  = (int)gridDim.x - fcB;
        int i = bid * 256 + threadIdx.x;
        int stride = nb * 256;
        for (int e = i; e < E; e += stride) {
            int r = eidx[e];
            int c = eidx[E + e];
            int slot = atomicAdd(&cnt[r], 1);
            if (slot < CAP) {
                slots[(size_t)r * CAP + slot] = c;
            } else {
                int p = atomicAdd(spillcnt, 1);
                if (p < SPILLCAP) { spill[2 * p] = r; spill[2 * p + 1] = c; }
            }
        }
    }
}

// ---------- gather4b: one wave/node; 16-lane groups, 4 edges/load; slots row fixed-stride ----------
__device__ inline void acc_bf8(const uint2* yb, int c, int ch4,
                               float& r0, float& r1, float& r2, float& r3) {
    uint2 u = yb[(size_t)c * 16 + ch4];             // 8 B/lane, 128 B per 16-lane group
    r0 += __uint_as_float(u.x << 16);
    r1 += __uint_as_float(u.x & 0xffff0000u);
    r2 += __uint_as_float(u.y << 16);
    r3 += __uint_as_float(u.y & 0xffff0000u);
}
__global__ __launch_bounds__(256) void gather4b(const int* __restrict__ cnt,
        const int* __restrict__ slots, const uint2* __restrict__ yb,
        float4* __restrict__ z4, int N) {
    int lane = threadIdx.x & 63;
    int node = (blockIdx.x << 2) + (threadIdx.x >> 6);
    if (node >= N) return;
    int deg = cnt[node];                 // single dependent index load (vs start/start+1)
    deg = deg > CAP ? CAP : deg;
    const int* srow = slots + (size_t)node * CAP;
    int sub = lane >> 4;
    int ch4 = lane & 15;
    float A0=0,A1=0,A2=0,A3=0, B0=0,B1=0,B2=0,B3=0,
          C0=0,C1=0,C2=0,C3=0, D0=0,D1=0,D2=0,D3=0;
    for (int j = 0; j < deg; j += 16) {
        int j0 = j + sub, j1 = j + 4 + sub, j2 = j + 8 + sub, j3 = j + 12 + sub;
        int c0 = (j0 < deg) ? srow[j0] : -1;
        int c1 = (j1 < deg) ? srow[j1] : -1;
        int c2 = (j2 < deg) ? srow[j2] : -1;
        int c3 = (j3 < deg) ? srow[j3] : -1;
        if (c0 >= 0) acc_bf8(yb, c0, ch4, A0, A1, A2, A3);
        if (c1 >= 0) acc_bf8(yb, c1, ch4, B0, B1, B2, B3);
        if (c2 >= 0) acc_bf8(yb, c2, ch4, C0, C1, C2, C3);
        if (c3 >= 0) acc_bf8(yb, c3, ch4, D0, D1, D2, D3);
    }
    float r0 = (A0 + B0) + (C0 + D0);
    float r1 = (A1 + B1) + (C1 + D1);
    float r2 = (A2 + B2) + (C2 + D2);
    float r3 = (A3 + B3) + (C3 + D3);
    r0 += __shfl_xor(r0, 16, 64); r0 += __shfl_xor(r0, 32, 64);
    r1 += __shfl_xor(r1, 16, 64); r1 += __shfl_xor(r1, 32, 64);
    r2 += __shfl_xor(r2, 16, 64); r2 += __shfl_xor(r2, 32, 64);
    r3 += __shfl_xor(r3, 16, 64); r3 += __shfl_xor(r3, 32, 64);
    if (lane < 16)
        z4[(size_t)node * 16 + ch4] = make_float4(r0, r1, r2, r3);
}

// ---------- spill_fix: add spilled edges (deg > CAP) atomically; normally 0 iters ----------
__global__ void spill_fix(const int* __restrict__ spillcnt, const int* __restrict__ spill,
                          const unsigned short* __restrict__ yb, float* __restrict__ z) {
    int n = *spillcnt;
    if (n > SPILLCAP) n = SPILLCAP;
    int lane = threadIdx.x & 63;
    int g  = (int)((blockIdx.x * blockDim.x + threadIdx.x) >> 6);
    int nG = (int)((gridDim.x * blockDim.x) >> 6);
    for (int i = g; i < n; i += nG) {
        int r = spill[2 * i], c = spill[2 * i + 1];
        unsigned short u = yb[(size_t)c * 64 + lane];
        atomicAdd(&z[(size_t)r * 64 + lane], __uint_as_float(((unsigned)u) << 16));
    }
}

// ---------- fallback (ws too small): fc f32 + atomic scatter ----------
__global__ void fc_kernel(const float* __restrict__ x, const float* __restrict__ Wfc,
                          float* __restrict__ y, int N) {
    __shared__ float sW[64][65];
    __shared__ float sX[4][64];
    for (int i = threadIdx.x; i < 64 * 64; i += 256) sW[i >> 6][i & 63] = Wfc[i];
    int r = threadIdx.x >> 6, co = threadIdx.x & 63;
    int gRow = (blockIdx.x << 2) + r;
    sX[r][co] = (gRow < N) ? x[gRow * 64 + co] : 0.f;
    __syncthreads();
    if (gRow >= N) return;
    float acc = 0.f;
#pragma unroll
    for (int k = 0; k < 64; ++k) acc = fmaf(sX[r][k], sW[co][k], acc);
    y[gRow * 64 + co] = acc;
}
__global__ void scatter_kernel(const int* __restrict__ eidx, const float* __restrict__ y,
                               float* __restrict__ z, int E) {
    int lane = threadIdx.x & 63;
    int g  = (int)((blockIdx.x * blockDim.x + threadIdx.x) >> 6);
    int nG = (int)((gridDim.x * blockDim.x) >> 6);
    for (int e = g; e < E; e += nG) {
        int r = eidx[e], c = eidx[E + e];
        atomicAdd(&z[r * 64 + lane], y[c * 64 + lane]);
    }
}

extern "C" void kernel_launch(void* const* d_in, const int* in_sizes, int n_in,
                              void* d_out, int out_size, void* d_ws, size_t ws_size,
                              hipStream_t stream) {
    const float* x    = (const float*)d_in[0];
    const int*   eidx = (const int*)d_in[1];
    const float* Wfc  = (const float*)d_in[3];   // d_in[2,4,5] unused (alpha==1)
    float*       z    = (float*)d_out;

    int N = in_sizes[0] / 64;
    int E = in_sizes[1] / 2;

    // workspace layout
    char* w = (char*)d_ws;
    size_t off = 0;
    int* cnt      = (int*)(w + off); off += (size_t)N * sizeof(int);
    int* spillcnt = (int*)(w + off); off += 256;                       // 1 int + pad
    int* spill    = (int*)(w + off); off += (size_t)2 * SPILLCAP * sizeof(int);
    off = (off + 255) & ~(size_t)255;
    int* slots    = (int*)(w + off); off += (size_t)N * CAP * sizeof(int);
    off = (off + 255) & ~(size_t)255;
    unsigned short* yb = (unsigned short*)(w + off); off += (size_t)N * 64 * sizeof(unsigned short);

    if (ws_size >= off) {
        zero_kernel<<<256, 256, 0, stream>>>(cnt, N);       // cnt
        zero_kernel<<<1, 64, 0, stream>>>(spillcnt, 1);     // spill counter
        int fcB = (N + 15) / 16;                            // 3125 fc blocks
        int bkB = 1024;                                     // bucket blocks
        fc_bucket<<<fcB + bkB, 256, 0, stream>>>(x, Wfc, yb, N, eidx, cnt, slots,
                                                 spill, spillcnt, E, fcB);
        gather4b<<<(N + 3) / 4, 256, 0, stream>>>(cnt, slots, (const uint2*)yb,
                                                  (float4*)z, N);
        spill_fix<<<64, 256, 0, stream>>>(spillcnt, spill, yb, z);
    } else {
        float* y = (float*)d_ws;
        hipMemsetAsync(d_out, 0, (size_t)out_size * sizeof(float), stream);
        fc_kernel<<<(N + 3) / 4, 256, 0, stream>>>(x, Wfc, y, N);
        scatter_kernel<<<4096, 256, 0, stream>>>(eidx, y, z, E);
    }
}

// Round 10
// 94.624 us; speedup vs baseline: 1.1989x; 1.1989x over previous
//
#include <hip/hip_runtime.h>
#include <hip/hip_bf16.h>

// z = segment_sum( (x @ W_fc^T)[col], row )  -- alpha==1 (softmax over singleton dim)
// Round 10: column-major slots[slot*N + r] fixes round 9's partial-line HBM
// write amplification (54 MB -> ~4 MB: each slot-plane is a dense 200 KB
// L2-resident region). Bucket blocks FIRST so they overlap fc blocks.
// Pipeline: zero -> bucket||fc -> gather4b -> spill_fix   (4 launches)

#define CAP 48
#define SPILLCAP 65536

__device__ inline unsigned short f2bf(float f) {
    __hip_bfloat16 h = __float2bfloat16(f);
    return *reinterpret_cast<unsigned short*>(&h);
}

// ---------- zero: cnt[N] + spillcnt (spillcnt = cnt+N, zeroed in same pass) ----------
__global__ void zero_kernel(int* __restrict__ a, int n) {
    int i = blockIdx.x * blockDim.x + threadIdx.x;
    int s = gridDim.x * blockDim.x;
    for (; i < n; i += s) a[i] = 0;
}

// ---------- fused: blocks [0,bkB) bucket edges; blocks [bkB,..) do fc ----------
__global__ __launch_bounds__(256) void fc_bucket(
        const float* __restrict__ x, const float* __restrict__ Wfc,
        unsigned short* __restrict__ y, int N,
        const int* __restrict__ eidx, int* __restrict__ cnt, int* __restrict__ slots,
        int* __restrict__ spill, int* __restrict__ spillcnt, int E, int bkB) {
    if ((int)blockIdx.x < bkB) {
        // ---- bucket: slot = atomicAdd(cnt[r]); slots[slot*N + r] = c (col-major!) ----
        int i = (int)blockIdx.x * 256 + threadIdx.x;
        int stride = bkB * 256;
        for (int e = i; e < E; e += stride) {
            int r = eidx[e];
            int c = eidx[E + e];
            int slot = atomicAdd(&cnt[r], 1);
            if (slot < CAP) {
                slots[(size_t)slot * N + r] = c;     // dense 200KB plane per slot
            } else {
                int p = atomicAdd(spillcnt, 1);
                if (p < SPILLCAP) { spill[2 * p] = r; spill[2 * p + 1] = c; }
            }
        }
    } else {
        // ---- fc: 16 rows/block, bf16 out ----
        __shared__ float sW[64][65];
        __shared__ float sX[16][64];
        for (int i = threadIdx.x; i < 4096; i += 256) sW[i >> 6][i & 63] = Wfc[i];
        int row0 = ((int)blockIdx.x - bkB) << 4;
        for (int i = threadIdx.x; i < 1024; i += 256) {
            int r = i >> 6, k = i & 63, gr = row0 + r;
            sX[r][k] = (gr < N) ? x[(size_t)gr * 64 + k] : 0.f;
        }
        __syncthreads();
        int co = threadIdx.x & 63;
        int rq = threadIdx.x >> 6;
        float a0 = 0, a1 = 0, a2 = 0, a3 = 0;
#pragma unroll
        for (int k = 0; k < 64; ++k) {
            float w = sW[co][k];
            a0 = fmaf(w, sX[4 * rq + 0][k], a0);
            a1 = fmaf(w, sX[4 * rq + 1][k], a1);
            a2 = fmaf(w, sX[4 * rq + 2][k], a2);
            a3 = fmaf(w, sX[4 * rq + 3][k], a3);
        }
        int g = row0 + 4 * rq;
        if (g + 3 < N) {
            y[(size_t)(g + 0) * 64 + co] = f2bf(a0);
            y[(size_t)(g + 1) * 64 + co] = f2bf(a1);
            y[(size_t)(g + 2) * 64 + co] = f2bf(a2);
            y[(size_t)(g + 3) * 64 + co] = f2bf(a3);
        } else {
            if (g + 0 < N) y[(size_t)(g + 0) * 64 + co] = f2bf(a0);
            if (g + 1 < N) y[(size_t)(g + 1) * 64 + co] = f2bf(a1);
            if (g + 2 < N) y[(size_t)(g + 2) * 64 + co] = f2bf(a2);
        }
    }
}

// ---------- gather4b: one wave/node; 16-lane groups, 4 edges in flight each ----------
__device__ inline void acc_bf8(const uint2* yb, int c, int ch4,
                               float& r0, float& r1, float& r2, float& r3) {
    uint2 u = yb[(size_t)c * 16 + ch4];             // 8 B/lane, 128 B per 16-lane group
    r0 += __uint_as_float(u.x << 16);
    r1 += __uint_as_float(u.x & 0xffff0000u);
    r2 += __uint_as_float(u.y << 16);
    r3 += __uint_as_float(u.y & 0xffff0000u);
}
__global__ __launch_bounds__(256) void gather4b(const int* __restrict__ cnt,
        const int* __restrict__ slots, const uint2* __restrict__ yb,
        float4* __restrict__ z4, int N) {
    int lane = threadIdx.x & 63;
    int node = (blockIdx.x << 2) + (threadIdx.x >> 6);
    if (node >= N) return;
    int deg = cnt[node];
    deg = deg > CAP ? CAP : deg;
    int sub = lane >> 4;
    int ch4 = lane & 15;
    float A0=0,A1=0,A2=0,A3=0, B0=0,B1=0,B2=0,B3=0,
          C0=0,C1=0,C2=0,C3=0, D0=0,D1=0,D2=0,D3=0;
    for (int j = 0; j < deg; j += 16) {
        int j0 = j + sub, j1 = j + 4 + sub, j2 = j + 8 + sub, j3 = j + 12 + sub;
        int c0 = (j0 < deg) ? slots[(size_t)j0 * N + node] : -1;  // 4B broadcast/group
        int c1 = (j1 < deg) ? slots[(size_t)j1 * N + node] : -1;
        int c2 = (j2 < deg) ? slots[(size_t)j2 * N + node] : -1;
        int c3 = (j3 < deg) ? slots[(size_t)j3 * N + node] : -1;
        if (c0 >= 0) acc_bf8(yb, c0, ch4, A0, A1, A2, A3);
        if (c1 >= 0) acc_bf8(yb, c1, ch4, B0, B1, B2, B3);
        if (c2 >= 0) acc_bf8(yb, c2, ch4, C0, C1, C2, C3);
        if (c3 >= 0) acc_bf8(yb, c3, ch4, D0, D1, D2, D3);
    }
    float r0 = (A0 + B0) + (C0 + D0);
    float r1 = (A1 + B1) + (C1 + D1);
    float r2 = (A2 + B2) + (C2 + D2);
    float r3 = (A3 + B3) + (C3 + D3);
    r0 += __shfl_xor(r0, 16, 64); r0 += __shfl_xor(r0, 32, 64);
    r1 += __shfl_xor(r1, 16, 64); r1 += __shfl_xor(r1, 32, 64);
    r2 += __shfl_xor(r2, 16, 64); r2 += __shfl_xor(r2, 32, 64);
    r3 += __shfl_xor(r3, 16, 64); r3 += __shfl_xor(r3, 32, 64);
    if (lane < 16)
        z4[(size_t)node * 16 + ch4] = make_float4(r0, r1, r2, r3);
}

// ---------- spill_fix: add spilled edges (deg > CAP) atomically; normally 0 iters ----------
__global__ void spill_fix(const int* __restrict__ spillcnt, const int* __restrict__ spill,
                          const unsigned short* __restrict__ yb, float* __restrict__ z) {
    int n = *spillcnt;
    if (n > SPILLCAP) n = SPILLCAP;
    int lane = threadIdx.x & 63;
    int g  = (int)((blockIdx.x * blockDim.x + threadIdx.x) >> 6);
    int nG = (int)((gridDim.x * blockDim.x) >> 6);
    for (int i = g; i < n; i += nG) {
        int r = spill[2 * i], c = spill[2 * i + 1];
        unsigned short u = yb[(size_t)c * 64 + lane];
        atomicAdd(&z[(size_t)r * 64 + lane], __uint_as_float(((unsigned)u) << 16));
    }
}

// ---------- fallback (ws too small): fc f32 + atomic scatter ----------
__global__ void fc_kernel(const float* __restrict__ x, const float* __restrict__ Wfc,
                          float* __restrict__ y, int N) {
    __shared__ float sW[64][65];
    __shared__ float sX[4][64];
    for (int i = threadIdx.x; i < 64 * 64; i += 256) sW[i >> 6][i & 63] = Wfc[i];
    int r = threadIdx.x >> 6, co = threadIdx.x & 63;
    int gRow = (blockIdx.x << 2) + r;
    sX[r][co] = (gRow < N) ? x[gRow * 64 + co] : 0.f;
    __syncthreads();
    if (gRow >= N) return;
    float acc = 0.f;
#pragma unroll
    for (int k = 0; k < 64; ++k) acc = fmaf(sX[r][k], sW[co][k], acc);
    y[gRow * 64 + co] = acc;
}
__global__ void scatter_kernel(const int* __restrict__ eidx, const float* __restrict__ y,
                               float* __restrict__ z, int E) {
    int lane = threadIdx.x & 63;
    int g  = (int)((blockIdx.x * blockDim.x + threadIdx.x) >> 6);
    int nG = (int)((gridDim.x * blockDim.x) >> 6);
    for (int e = g; e < E; e += nG) {
        int r = eidx[e], c = eidx[E + e];
        atomicAdd(&z[r * 64 + lane], y[c * 64 + lane]);
    }
}

extern "C" void kernel_launch(void* const* d_in, const int* in_sizes, int n_in,
                              void* d_out, int out_size, void* d_ws, size_t ws_size,
                              hipStream_t stream) {
    const float* x    = (const float*)d_in[0];
    const int*   eidx = (const int*)d_in[1];
    const float* Wfc  = (const float*)d_in[3];   // d_in[2,4,5] unused (alpha==1)
    float*       z    = (float*)d_out;

    int N = in_sizes[0] / 64;
    int E = in_sizes[1] / 2;

    // workspace layout: cnt[N] | spillcnt[1] (contiguous, zeroed together) | spill | slots | yb
    char* w = (char*)d_ws;
    size_t off = 0;
    int* cnt      = (int*)(w + off); off += (size_t)N * sizeof(int);
    int* spillcnt = (int*)(w + off); off += sizeof(int);
    off = (off + 255) & ~(size_t)255;
    int* spill    = (int*)(w + off); off += (size_t)2 * SPILLCAP * sizeof(int);
    off = (off + 255) & ~(size_t)255;
    int* slots    = (int*)(w + off); off += (size_t)CAP * N * sizeof(int);
    off = (off + 255) & ~(size_t)255;
    unsigned short* yb = (unsigned short*)(w + off); off += (size_t)N * 64 * sizeof(unsigned short);

    if (ws_size >= off) {
        zero_kernel<<<512, 256, 0, stream>>>(cnt, N + 1);   // cnt + spillcnt
        int bkB = 1024;                                     // bucket blocks (first!)
        int fcB = (N + 15) / 16;                            // fc blocks
        fc_bucket<<<bkB + fcB, 256, 0, stream>>>(x, Wfc, yb, N, eidx, cnt, slots,
                                                 spill, spillcnt, E, bkB);
        gather4b<<<(N + 3) / 4, 256, 0, stream>>>(cnt, slots, (const uint2*)yb,
                                                  (float4*)z, N);
        spill_fix<<<64, 256, 0, stream>>>(spillcnt, spill, yb, z);
    } else {
        float* y = (float*)d_ws;
        hipMemsetAsync(d_out, 0, (size_t)out_size * sizeof(float), stream);
        fc_kernel<<<(N + 3) / 4, 256, 0, stream>>>(x, Wfc, y, N);
        scatter_kernel<<<4096, 256, 0, stream>>>(eidx, y, z, E);
    }
}

// Round 11
// 86.733 us; speedup vs baseline: 1.3080x; 1.0910x over previous
//
#include <hip/hip_runtime.h>
#include <hip/hip_bf16.h>

// z = segment_sum( (x @ W_fc^T)[col], row )  -- alpha==1 (softmax over singleton dim)
// Round 11: XCD-partitioned bucketing. Round 10's col-major slots still wrote
// 52 MB: the 7 MB active region is shared by 8 non-coherent L2s -> each XCD
// writes back its own partial lines (~1 x 4B per line per XCD). Fix: blocks on
// XCD p (= blockIdx&7, round-robin dispatch) only process edges with
// r in partition p -> slots/cnt writes localize to ~900 KB per XCD L2.
// Pipeline: zero -> bucket||fc -> gather4b -> spill_fix   (4 launches)

#define CAP 48
#define SPILLCAP 65536
#define NPART 8

__device__ inline unsigned short f2bf(float f) {
    __hip_bfloat16 h = __float2bfloat16(f);
    return *reinterpret_cast<unsigned short*>(&h);
}

// ---------- zero: cnt[N] + spillcnt ----------
__global__ void zero_kernel(int* __restrict__ a, int n) {
    int i = blockIdx.x * blockDim.x + threadIdx.x;
    int s = gridDim.x * blockDim.x;
    for (; i < n; i += s) a[i] = 0;
}

// ---------- fused: blocks [0,bkB) bucket edges (XCD-partitioned); rest do fc ----------
__global__ __launch_bounds__(256) void fc_bucket(
        const float* __restrict__ x, const float* __restrict__ Wfc,
        unsigned short* __restrict__ y, int N,
        const int* __restrict__ eidx, int* __restrict__ cnt, int* __restrict__ slots,
        int* __restrict__ spill, int* __restrict__ spillcnt, int E, int bkB) {
    if ((int)blockIdx.x < bkB) {
        // ---- bucket, destination-partitioned by XCD ----
        int b    = (int)blockIdx.x;
        int p    = b & (NPART - 1);          // assumed XCD of this block (round-robin)
        int sub  = b >> 3;                   // index among blocks of this partition
        int nsub = bkB >> 3;
        int psz  = (N + NPART - 1) / NPART;
        int lo   = p * psz;
        int hi   = lo + psz; if (hi > N) hi = N;
        int i = sub * 256 + threadIdx.x;
        int stride = nsub * 256;
        for (int e = i; e < E; e += stride) {
            int r = eidx[e];                 // full-wave coalesced scan
            if (r >= lo && r < hi) {         // ~1/8 lanes proceed
                int c = eidx[E + e];
                int slot = atomicAdd(&cnt[r], 1);    // L2-local atomic
                if (slot < CAP) {
                    slots[(size_t)slot * N + r] = c; // write stays in XCD-p's L2
                } else {
                    int q = atomicAdd(spillcnt, 1);
                    if (q < SPILLCAP) { spill[2 * q] = r; spill[2 * q + 1] = c; }
                }
            }
        }
    } else {
        // ---- fc: 16 rows/block, bf16 out ----
        __shared__ float sW[64][65];
        __shared__ float sX[16][64];
        for (int i = threadIdx.x; i < 4096; i += 256) sW[i >> 6][i & 63] = Wfc[i];
        int row0 = ((int)blockIdx.x - bkB) << 4;
        for (int i = threadIdx.x; i < 1024; i += 256) {
            int r = i >> 6, k = i & 63, gr = row0 + r;
            sX[r][k] = (gr < N) ? x[(size_t)gr * 64 + k] : 0.f;
        }
        __syncthreads();
        int co = threadIdx.x & 63;
        int rq = threadIdx.x >> 6;
        float a0 = 0, a1 = 0, a2 = 0, a3 = 0;
#pragma unroll
        for (int k = 0; k < 64; ++k) {
            float w = sW[co][k];
            a0 = fmaf(w, sX[4 * rq + 0][k], a0);
            a1 = fmaf(w, sX[4 * rq + 1][k], a1);
            a2 = fmaf(w, sX[4 * rq + 2][k], a2);
            a3 = fmaf(w, sX[4 * rq + 3][k], a3);
        }
        int g = row0 + 4 * rq;
        if (g + 3 < N) {
            y[(size_t)(g + 0) * 64 + co] = f2bf(a0);
            y[(size_t)(g + 1) * 64 + co] = f2bf(a1);
            y[(size_t)(g + 2) * 64 + co] = f2bf(a2);
            y[(size_t)(g + 3) * 64 + co] = f2bf(a3);
        } else {
            if (g + 0 < N) y[(size_t)(g + 0) * 64 + co] = f2bf(a0);
            if (g + 1 < N) y[(size_t)(g + 1) * 64 + co] = f2bf(a1);
            if (g + 2 < N) y[(size_t)(g + 2) * 64 + co] = f2bf(a2);
        }
    }
}

// ---------- gather4b: one wave/node; 16-lane groups, 4 edges in flight each ----------
__device__ inline void acc_bf8(const uint2* yb, int c, int ch4,
                               float& r0, float& r1, float& r2, float& r3) {
    uint2 u = yb[(size_t)c * 16 + ch4];             // 8 B/lane, 128 B per 16-lane group
    r0 += __uint_as_float(u.x << 16);
    r1 += __uint_as_float(u.x & 0xffff0000u);
    r2 += __uint_as_float(u.y << 16);
    r3 += __uint_as_float(u.y & 0xffff0000u);
}
__global__ __launch_bounds__(256) void gather4b(const int* __restrict__ cnt,
        const int* __restrict__ slots, const uint2* __restrict__ yb,
        float4* __restrict__ z4, int N) {
    int lane = threadIdx.x & 63;
    int node = (blockIdx.x << 2) + (threadIdx.x >> 6);
    if (node >= N) return;
    int deg = cnt[node];
    deg = deg > CAP ? CAP : deg;
    int sub = lane >> 4;
    int ch4 = lane & 15;
    float A0=0,A1=0,A2=0,A3=0, B0=0,B1=0,B2=0,B3=0,
          C0=0,C1=0,C2=0,C3=0, D0=0,D1=0,D2=0,D3=0;
    for (int j = 0; j < deg; j += 16) {
        int j0 = j + sub, j1 = j + 4 + sub, j2 = j + 8 + sub, j3 = j + 12 + sub;
        int c0 = (j0 < deg) ? slots[(size_t)j0 * N + node] : -1;  // broadcast/group
        int c1 = (j1 < deg) ? slots[(size_t)j1 * N + node] : -1;
        int c2 = (j2 < deg) ? slots[(size_t)j2 * N + node] : -1;
        int c3 = (j3 < deg) ? slots[(size_t)j3 * N + node] : -1;
        if (c0 >= 0) acc_bf8(yb, c0, ch4, A0, A1, A2, A3);
        if (c1 >= 0) acc_bf8(yb, c1, ch4, B0, B1, B2, B3);
        if (c2 >= 0) acc_bf8(yb, c2, ch4, C0, C1, C2, C3);
        if (c3 >= 0) acc_bf8(yb, c3, ch4, D0, D1, D2, D3);
    }
    float r0 = (A0 + B0) + (C0 + D0);
    float r1 = (A1 + B1) + (C1 + D1);
    float r2 = (A2 + B2) + (C2 + D2);
    float r3 = (A3 + B3) + (C3 + D3);
    r0 += __shfl_xor(r0, 16, 64); r0 += __shfl_xor(r0, 32, 64);
    r1 += __shfl_xor(r1, 16, 64); r1 += __shfl_xor(r1, 32, 64);
    r2 += __shfl_xor(r2, 16, 64); r2 += __shfl_xor(r2, 32, 64);
    r3 += __shfl_xor(r3, 16, 64); r3 += __shfl_xor(r3, 32, 64);
    if (lane < 16)
        z4[(size_t)node * 16 + ch4] = make_float4(r0, r1, r2, r3);
}

// ---------- spill_fix: add spilled edges (deg > CAP) atomically; normally 0 iters ----------
__global__ void spill_fix(const int* __restrict__ spillcnt, const int* __restrict__ spill,
                          const unsigned short* __restrict__ yb, float* __restrict__ z) {
    int n = *spillcnt;
    if (n > SPILLCAP) n = SPILLCAP;
    int lane = threadIdx.x & 63;
    int g  = (int)((blockIdx.x * blockDim.x + threadIdx.x) >> 6);
    int nG = (int)((gridDim.x * blockDim.x) >> 6);
    for (int i = g; i < n; i += nG) {
        int r = spill[2 * i], c = spill[2 * i + 1];
        unsigned short u = yb[(size_t)c * 64 + lane];
        atomicAdd(&z[(size_t)r * 64 + lane], __uint_as_float(((unsigned)u) << 16));
    }
}

// ---------- fallback (ws too small): fc f32 + atomic scatter ----------
__global__ void fc_kernel(const float* __restrict__ x, const float* __restrict__ Wfc,
                          float* __restrict__ y, int N) {
    __shared__ float sW[64][65];
    __shared__ float sX[4][64];
    for (int i = threadIdx.x; i < 64 * 64; i += 256) sW[i >> 6][i & 63] = Wfc[i];
    int r = threadIdx.x >> 6, co = threadIdx.x & 63;
    int gRow = (blockIdx.x << 2) + r;
    sX[r][co] = (gRow < N) ? x[gRow * 64 + co] : 0.f;
    __syncthreads();
    if (gRow >= N) return;
    float acc = 0.f;
#pragma unroll
    for (int k = 0; k < 64; ++k) acc = fmaf(sX[r][k], sW[co][k], acc);
    y[gRow * 64 + co] = acc;
}
__global__ void scatter_kernel(const int* __restrict__ eidx, const float* __restrict__ y,
                               float* __restrict__ z, int E) {
    int lane = threadIdx.x & 63;
    int g  = (int)((blockIdx.x * blockDim.x + threadIdx.x) >> 6);
    int nG = (int)((gridDim.x * blockDim.x) >> 6);
    for (int e = g; e < E; e += nG) {
        int r = eidx[e], c = eidx[E + e];
        atomicAdd(&z[r * 64 + lane], y[c * 64 + lane]);
    }
}

extern "C" void kernel_launch(void* const* d_in, const int* in_sizes, int n_in,
                              void* d_out, int out_size, void* d_ws, size_t ws_size,
                              hipStream_t stream) {
    const float* x    = (const float*)d_in[0];
    const int*   eidx = (const int*)d_in[1];
    const float* Wfc  = (const float*)d_in[3];   // d_in[2,4,5] unused (alpha==1)
    float*       z    = (float*)d_out;

    int N = in_sizes[0] / 64;
    int E = in_sizes[1] / 2;

    // workspace: cnt[N] | spillcnt[1] | spill | slots (col-major CAP x N) | yb
    char* w = (char*)d_ws;
    size_t off = 0;
    int* cnt      = (int*)(w + off); off += (size_t)N * sizeof(int);
    int* spillcnt = (int*)(w + off); off += sizeof(int);
    off = (off + 255) & ~(size_t)255;
    int* spill    = (int*)(w + off); off += (size_t)2 * SPILLCAP * sizeof(int);
    off = (off + 255) & ~(size_t)255;
    int* slots    = (int*)(w + off); off += (size_t)CAP * N * sizeof(int);
    off = (off + 255) & ~(size_t)255;
    unsigned short* yb = (unsigned short*)(w + off); off += (size_t)N * 64 * sizeof(unsigned short);

    if (ws_size >= off) {
        zero_kernel<<<512, 256, 0, stream>>>(cnt, N + 1);   // cnt + spillcnt
        int bkB = 1024;                                     // bucket blocks (first; %8 = XCD)
        int fcB = (N + 15) / 16;                            // fc blocks
        fc_bucket<<<bkB + fcB, 256, 0, stream>>>(x, Wfc, yb, N, eidx, cnt, slots,
                                                 spill, spillcnt, E, bkB);
        gather4b<<<(N + 3) / 4, 256, 0, stream>>>(cnt, slots, (const uint2*)yb,
                                                  (float4*)z, N);
        spill_fix<<<64, 256, 0, stream>>>(spillcnt, spill, yb, z);
    } else {
        float* y = (float*)d_ws;
        hipMemsetAsync(d_out, 0, (size_t)out_size * sizeof(float), stream);
        fc_kernel<<<(N + 3) / 4, 256, 0, stream>>>(x, Wfc, y, N);
        scatter_kernel<<<4096, 256, 0, stream>>>(eidx, y, z, E);
    }
}